// Round 8
// baseline (252.450 us; speedup 1.0000x reference)
//
#include <hip/hip_runtime.h>
#include <hip/hip_fp16.h>
#include <math.h>

#define M_  8
#define N_  1024
#define D_  512
#define H_  512
#define PI_ 3.14159265358979323846f

// ---------------- ws layouts (in floats) ----------------
// FAST path (needs ~16.8 MB): CHS table + small buffers.
static const size_t OFF_CHS = 0;                              // 4.19M half2 = 4.19M float slots (16 MB)
static const size_t OFF_SIG = OFF_CHS + (size_t)M_*N_*D_;     // 1 (pad 64)
static const size_t OFF_MA  = OFF_SIG + 64;                   // 8*512  } contiguous: zeroed together
static const size_t OFF_MZR = OFF_MA  + (size_t)M_*D_;        // 8*512  }
static const size_t OFF_MZI = OFF_MZR + (size_t)M_*D_;        // 8*512  }
static const size_t OFF_H   = OFF_MZI + (size_t)M_*D_;        // 8*512
static const size_t OFF_Q   = OFF_H   + (size_t)M_*H_;
static const size_t OFF_K   = OFF_Q   + (size_t)M_*H_;
static const size_t OFF_V   = OFF_K   + (size_t)M_*H_;
static const size_t OFF_ATT = OFF_V   + (size_t)M_*H_;        // 512
static const size_t FAST_FLOATS = OFF_ATT + 512;
// FALLBACK path (~120 KB): same minus CHS.
static const size_t FB_SIG = 0;
static const size_t FB_MA  = FB_SIG + 64;
static const size_t FB_MZR = FB_MA  + (size_t)M_*D_;
static const size_t FB_MZI = FB_MZR + (size_t)M_*D_;
static const size_t FB_H   = FB_MZI + (size_t)M_*D_;
static const size_t FB_Q   = FB_H   + (size_t)M_*H_;
static const size_t FB_K   = FB_Q   + (size_t)M_*H_;
static const size_t FB_V   = FB_K   + (size_t)M_*H_;
static const size_t FB_ATT = FB_V   + (size_t)M_*H_;

struct F8   { float4 a, b; };        // 8 consecutive floats (32 B)
struct H2x8 { __half2 h[8]; };       // 8 consecutive half2 (32 B)

__device__ __forceinline__ void unp8(float* d, const F8& v) {
    d[0]=v.a.x; d[1]=v.a.y; d[2]=v.a.z; d[3]=v.a.w;
    d[4]=v.b.x; d[5]=v.b.y; d[6]=v.b.z; d[7]=v.b.w;
}

// ---------------- fast-path kernels ----------------

// blocks 0..2047: chs = (cos th, sin th) half2, th = phase0 + 0.1*pv (8 elems/thread).
//   total elements = 8*1024*512 = 4,194,304 = 2048 blocks * 256 thr * 8.
// blocks 0..5 also zero the 12288-float accumulator region. block 2048: sigmax.
__global__ __launch_bounds__(256) void prep_kernel(const float* __restrict__ phase0,
                                                   const float* __restrict__ pv,
                                                   const float* __restrict__ x,
                                                   __half2* __restrict__ chs,
                                                   float* __restrict__ acczero,
                                                   float* __restrict__ sigmax) {
    const int bid = blockIdx.x, tid = threadIdx.x;
    if (bid < 2048) {
        const size_t e = ((size_t)bid * 256 + tid) * 8;       // max 4,194,296
        float ph[8], pw[8];
        unp8(ph, *reinterpret_cast<const F8*>(phase0 + e));
        unp8(pw, *reinterpret_cast<const F8*>(pv + e));
        H2x8 out;
        #pragma unroll
        for (int s = 0; s < 8; ++s) {
            const float th = fmaf(0.1f, pw[s], ph[s]);
            out.h[s] = __floats2half2_rn(__cosf(th), __sinf(th));
        }
        *reinterpret_cast<H2x8*>(chs + e) = out;
        if (bid < 6) {
            F8 z; z.a = make_float4(0.f,0.f,0.f,0.f); z.b = z.a;
            *reinterpret_cast<F8*>(acczero + (size_t)bid * 2048 + (size_t)tid * 8) = z;
        }
    } else if (tid < 64) {
        float v[8];
        unp8(v, *reinterpret_cast<const F8*>(x + (size_t)tid * 8));
        float mx = 0.f;
        #pragma unroll
        for (int s = 0; s < 8; ++s) mx = fmaxf(mx, fabsf(v[s]));
        #pragma unroll
        for (int off = 32; off; off >>= 1) mx = fmaxf(mx, __shfl_down(mx, off));
        if (tid == 0) *sigmax = mx;
    }
}

// 1024 blocks x 512 thr. m = bid&7 (XCD pinning), g = bid>>3 in [0,128). 1 cell per wave.
__global__ __launch_bounds__(512) void micro_kernel(
    const float* __restrict__ amp0, const __half2* __restrict__ chs,
    const float* __restrict__ x, const float* __restrict__ sigmax_p,
    const int* __restrict__ nbr_idx, const float* __restrict__ nbr_mask,
    const int* __restrict__ step_p,
    float* __restrict__ mA, float* __restrict__ mZr, float* __restrict__ mZi, int K)
{
    const int m = blockIdx.x & 7;
    const int g = blockIdx.x >> 3;
    const int wid  = threadIdx.x >> 6;
    const int lane = threadIdx.x & 63;
    const int i = (g << 3) + wid;            // cell 0..1023

    __shared__ float accA[D_], accZr[D_], accZi[D_];
    for (int idx = threadIdx.x; idx < D_; idx += 512) { accA[idx]=0.f; accZr[idx]=0.f; accZi[idx]=0.f; }
    __syncthreads();

    const float t  = 0.1f * (float)(*step_p);
    const float sm = *sigmax_p;

    float pp[8];
    unp8(pp, *reinterpret_cast<const F8*>(x + (size_t)lane * 8));
    #pragma unroll
    for (int s = 0; s < 8; ++s) pp[s] = pp[s] / (sm + 1e-8f) * (PI_ * 0.1f);

    const size_t mrow = (size_t)m * N_;

    // valid-neighbor count (mask = 1.0 for first L entries, prefix-packed)
    int L = 0;
    for (int k = 0; k < K; ++k) L += (nbr_mask[i * K + k] > 0.f) ? 1 : 0;

    float SA[8], SB[8], SC[8];
    #pragma unroll
    for (int s = 0; s < 8; ++s) { SA[s]=0.f; SB[s]=0.f; SC[s]=0.f; }
    float best = -1e30f; int midx = 0;

    for (int k = 0; k < L; ++k) {
        const int nb = nbr_idx[i * K + k];
        const size_t noff = (mrow + nb) * (size_t)D_ + (size_t)lane * 8;
        float aN[8];
        unp8(aN, *reinterpret_cast<const F8*>(amp0 + noff));
        const H2x8 hx = *reinterpret_cast<const H2x8*>(chs + noff);
        #pragma unroll
        for (int s = 0; s < 8; ++s) {
            const float2 cs = __half22float2(hx.h[s]);
            const float ac = aN[s] * cs.x, as_ = aN[s] * cs.y;
            SA[s] = fmaf(ac,  cs.x, SA[s]);
            SB[s] = fmaf(ac,  cs.y, SB[s]);
            SC[s] = fmaf(as_, cs.y, SC[s]);
        }
        // in-wave absum (argmax key): full-row sum of amp (rotation-invariant)
        float rs = ((aN[0]+aN[1])+(aN[2]+aN[3])) + ((aN[4]+aN[5])+(aN[6]+aN[7]));
        #pragma unroll
        for (int off = 1; off < 64; off <<= 1) rs += __shfl_xor(rs, off);
        const bool sel = rs > best;       // first-max (strict >), lane-uniform
        best = sel ? rs : best;
        midx = sel ? nb : midx;
    }
    const float f = 0.03f / fmaxf((float)L, 1.f);   // 0.3 * 0.1 / cnt

    // own state + interference
    float nre[8], nim[8];
    {
        const size_t ooff = (mrow + i) * (size_t)D_ + (size_t)lane * 8;
        float aO[8];
        unp8(aO, *reinterpret_cast<const F8*>(amp0 + ooff));
        const H2x8 hx = *reinterpret_cast<const H2x8*>(chs + ooff);
        #pragma unroll
        for (int s = 0; s < 8; ++s) {
            const float2 cs = __half22float2(hx.h[s]);
            nre[s] = 0.7f * aO[s] * cs.x + f * (cs.x * SA[s] + cs.y * SB[s]);
            nim[s] = 0.7f * aO[s] * cs.y + f * (cs.x * SB[s] + cs.y * SC[s]);
        }
    }
    // morph = new * conj(src) / |new|
    {
        const size_t soff = (mrow + midx) * (size_t)D_ + (size_t)lane * 8;
        float aS[8];
        unp8(aS, *reinterpret_cast<const F8*>(amp0 + soff));
        const H2x8 hx = *reinterpret_cast<const H2x8*>(chs + soff);
        #pragma unroll
        for (int s = 0; s < 8; ++s) {
            const float2 cs = __half22float2(hx.h[s]);
            const float sre = aS[s] * cs.x, sim = aS[s] * cs.y;
            const float inv = __builtin_amdgcn_rcpf(sqrtf(nre[s]*nre[s] + nim[s]*nim[s]));
            const float mre = (nre[s] * sre + nim[s] * sim) * inv;
            const float mim = (nim[s] * sre - nre[s] * sim) * inv;
            nre[s] = fmaf(0.02f, mre, nre[s]);
            nim[s] = fmaf(0.02f, mim, nim[s]);
        }
    }

    const float wf = 1.f + 0.02f * __sinf(t + 2.f * PI_ * (float)i / (float)N_);
    const float scale_i = 0.1f / (1.f + 0.1f * (float)i);

    float ampn[8], rm = 0.f;
    #pragma unroll
    for (int s = 0; s < 8; ++s) {
        nre[s] *= wf; nim[s] *= wf;
        ampn[s] = sqrtf(nre[s]*nre[s] + nim[s]*nim[s]);
        rm = fmaxf(rm, ampn[s]);
    }
    #pragma unroll
    for (int off = 1; off < 64; off <<= 1) rm = fmaxf(rm, __shfl_xor(rm, off));
    const float rinv = __builtin_amdgcn_rcpf(rm + 1e-8f);

    #pragma unroll
    for (int s = 0; s < 8; ++s) {
        const float anorm = ampn[s] * rinv;
        const float iamp  = __builtin_amdgcn_rcpf(ampn[s]);
        const float ure = nre[s] * iamp, uim = nim[s] * iamp;
        const float d  = pp[s] * scale_i;            // |d| <= 0.0314
        const float d2 = d * d;
        const float cd = 1.f - 0.5f * d2;
        const float sd = d * (1.f - 0.16666667f * d2);
        const int p = (s << 6) + lane;               // transposed slot: conflict-free ds_add
        atomicAdd(&accA[p],  anorm);
        atomicAdd(&accZr[p], ure * cd - uim * sd);
        atomicAdd(&accZi[p], ure * sd + uim * cd);
    }
    __syncthreads();
    const int j = threadIdx.x;                       // logical j
    const int p = ((j & 7) << 6) + (j >> 3);         // physical slot of logical j
    atomicAdd(&mA [m * D_ + j], accA[p]);
    atomicAdd(&mZr[m * D_ + j], accZr[p]);
    atomicAdd(&mZi[m * D_ + j], accZi[p]);
}

// ---------------- fallback-path kernels (no CHS table) ----------------

// 7 blocks x 256: blocks 0..5 zero accumulators; block 6 computes sigmax.
__global__ __launch_bounds__(256) void zero_sig_kernel(const float* __restrict__ x,
                                                       float* __restrict__ acczero,
                                                       float* __restrict__ sigmax) {
    const int bid = blockIdx.x, tid = threadIdx.x;
    if (bid < 6) {
        F8 z; z.a = make_float4(0.f,0.f,0.f,0.f); z.b = z.a;
        *reinterpret_cast<F8*>(acczero + (size_t)bid * 2048 + (size_t)tid * 8) = z;
    } else if (tid < 64) {
        float v[8];
        unp8(v, *reinterpret_cast<const F8*>(x + (size_t)tid * 8));
        float mx = 0.f;
        #pragma unroll
        for (int s = 0; s < 8; ++s) mx = fmaxf(mx, fabsf(v[s]));
        #pragma unroll
        for (int off = 32; off; off >>= 1) mx = fmaxf(mx, __shfl_down(mx, off));
        if (tid == 0) *sigmax = mx;
    }
}

__global__ __launch_bounds__(512) void micro_fb_kernel(
    const float* __restrict__ amp0, const float* __restrict__ phase0,
    const float* __restrict__ pvel,
    const float* __restrict__ x, const float* __restrict__ sigmax_p,
    const int* __restrict__ nbr_idx, const float* __restrict__ nbr_mask,
    const int* __restrict__ step_p,
    float* __restrict__ mA, float* __restrict__ mZr, float* __restrict__ mZi, int K)
{
    const int m = blockIdx.x & 7;
    const int g = blockIdx.x >> 3;
    const int wid  = threadIdx.x >> 6;
    const int lane = threadIdx.x & 63;
    const int i = (g << 3) + wid;

    __shared__ float accA[D_], accZr[D_], accZi[D_];
    for (int idx = threadIdx.x; idx < D_; idx += 512) { accA[idx]=0.f; accZr[idx]=0.f; accZi[idx]=0.f; }
    __syncthreads();

    const float t  = 0.1f * (float)(*step_p);
    const float sm = *sigmax_p;

    float pp[8];
    unp8(pp, *reinterpret_cast<const F8*>(x + (size_t)lane * 8));
    #pragma unroll
    for (int s = 0; s < 8; ++s) pp[s] = pp[s] / (sm + 1e-8f) * (PI_ * 0.1f);

    const size_t mrow = (size_t)m * N_;

    int L = 0;
    for (int k = 0; k < K; ++k) L += (nbr_mask[i * K + k] > 0.f) ? 1 : 0;

    float SA[8], SB[8], SC[8];
    #pragma unroll
    for (int s = 0; s < 8; ++s) { SA[s]=0.f; SB[s]=0.f; SC[s]=0.f; }
    float best = -1e30f; int midx = 0;

    for (int k = 0; k < L; ++k) {
        const int nb = nbr_idx[i * K + k];
        const size_t noff = (mrow + nb) * (size_t)D_ + (size_t)lane * 8;
        float aN[8], phN[8], pwN[8];
        unp8(aN, *reinterpret_cast<const F8*>(amp0 + noff));
        unp8(phN, *reinterpret_cast<const F8*>(phase0 + noff));
        unp8(pwN, *reinterpret_cast<const F8*>(pvel + noff));
        #pragma unroll
        for (int s = 0; s < 8; ++s) {
            const float th = fmaf(0.1f, pwN[s], phN[s]);
            const float cn = __cosf(th), sn = __sinf(th);
            const float ac = aN[s] * cn, as_ = aN[s] * sn;
            SA[s] = fmaf(ac,  cn, SA[s]);
            SB[s] = fmaf(ac,  sn, SB[s]);
            SC[s] = fmaf(as_, sn, SC[s]);
        }
        float rs = ((aN[0]+aN[1])+(aN[2]+aN[3])) + ((aN[4]+aN[5])+(aN[6]+aN[7]));
        #pragma unroll
        for (int off = 1; off < 64; off <<= 1) rs += __shfl_xor(rs, off);
        const bool sel = rs > best;
        best = sel ? rs : best;
        midx = sel ? nb : midx;
    }
    const float f = 0.03f / fmaxf((float)L, 1.f);

    float nre[8], nim[8];
    {
        const size_t ooff = (mrow + i) * (size_t)D_ + (size_t)lane * 8;
        float aO[8], ph[8], pw[8];
        unp8(aO, *reinterpret_cast<const F8*>(amp0 + ooff));
        unp8(ph, *reinterpret_cast<const F8*>(phase0 + ooff));
        unp8(pw, *reinterpret_cast<const F8*>(pvel + ooff));
        #pragma unroll
        for (int s = 0; s < 8; ++s) {
            const float th = fmaf(0.1f, pw[s], ph[s]);
            const float c = __cosf(th), sn = __sinf(th);
            nre[s] = 0.7f * aO[s] * c  + f * (c * SA[s] + sn * SB[s]);
            nim[s] = 0.7f * aO[s] * sn + f * (c * SB[s] + sn * SC[s]);
        }
    }
    {
        const size_t soff = (mrow + midx) * (size_t)D_ + (size_t)lane * 8;
        float aS[8], ph[8], pw[8];
        unp8(aS, *reinterpret_cast<const F8*>(amp0 + soff));
        unp8(ph, *reinterpret_cast<const F8*>(phase0 + soff));
        unp8(pw, *reinterpret_cast<const F8*>(pvel + soff));
        #pragma unroll
        for (int s = 0; s < 8; ++s) {
            const float th = fmaf(0.1f, pw[s], ph[s]);
            const float c = __cosf(th), sn = __sinf(th);
            const float sre = aS[s] * c, sim = aS[s] * sn;
            const float inv = __builtin_amdgcn_rcpf(sqrtf(nre[s]*nre[s] + nim[s]*nim[s]));
            const float mre = (nre[s] * sre + nim[s] * sim) * inv;
            const float mim = (nim[s] * sre - nre[s] * sim) * inv;
            nre[s] = fmaf(0.02f, mre, nre[s]);
            nim[s] = fmaf(0.02f, mim, nim[s]);
        }
    }

    const float wf = 1.f + 0.02f * __sinf(t + 2.f * PI_ * (float)i / (float)N_);
    const float scale_i = 0.1f / (1.f + 0.1f * (float)i);

    float ampn[8], rm = 0.f;
    #pragma unroll
    for (int s = 0; s < 8; ++s) {
        nre[s] *= wf; nim[s] *= wf;
        ampn[s] = sqrtf(nre[s]*nre[s] + nim[s]*nim[s]);
        rm = fmaxf(rm, ampn[s]);
    }
    #pragma unroll
    for (int off = 1; off < 64; off <<= 1) rm = fmaxf(rm, __shfl_xor(rm, off));
    const float rinv = __builtin_amdgcn_rcpf(rm + 1e-8f);

    #pragma unroll
    for (int s = 0; s < 8; ++s) {
        const float anorm = ampn[s] * rinv;
        const float iamp  = __builtin_amdgcn_rcpf(ampn[s]);
        const float ure = nre[s] * iamp, uim = nim[s] * iamp;
        const float d  = pp[s] * scale_i;
        const float d2 = d * d;
        const float cd = 1.f - 0.5f * d2;
        const float sd = d * (1.f - 0.16666667f * d2);
        const int p = (s << 6) + lane;
        atomicAdd(&accA[p],  anorm);
        atomicAdd(&accZr[p], ure * cd - uim * sd);
        atomicAdd(&accZi[p], ure * sd + uim * cd);
    }
    __syncthreads();
    const int j = threadIdx.x;
    const int p = ((j & 7) << 6) + (j >> 3);
    atomicAdd(&mA [m * D_ + j], accA[p]);
    atomicAdd(&mZr[m * D_ + j], accZr[p]);
    atomicAdd(&mZi[m * D_ + j], accZi[p]);
}

// ---------------- shared macro-side kernels ----------------

// fused GRU: gates + nonlinearity -> h.  128 blocks x 256 thr, wave = output dim d.
__global__ __launch_bounds__(256) void macro_kernel(
    const float* __restrict__ mA, const float* __restrict__ h0,
    const float* __restrict__ w_ih, const float* __restrict__ b_ih,
    const float* __restrict__ w_hh, const float* __restrict__ b_hh,
    float* __restrict__ h)
{
    __shared__ float vx[M_ * H_], vh[M_ * H_];
    for (int idx = threadIdx.x; idx < M_ * H_; idx += 256) {
        vx[idx] = mA[idx] * (1.f / (float)N_);       // micro_out = A-sum / 1024
        vh[idx] = h0[idx];
    }
    __syncthreads();
    const int wid = threadIdx.x >> 6, lane = threadIdx.x & 63;
    const int d = (blockIdx.x << 2) + wid;   // 0..511
    float wr[6][8];
    #pragma unroll
    for (int rr = 0; rr < 3; ++rr) {
        const size_t row = (size_t)(d + rr * H_) * H_;
        #pragma unroll
        for (int kk = 0; kk < 8; ++kk) {
            wr[rr][kk]     = w_ih[row + kk * 64 + lane];
            wr[rr + 3][kk] = w_hh[row + kk * 64 + lane];
        }
    }
    const float br = b_ih[d], bz = b_ih[d + H_], bn = b_ih[d + 2 * H_];
    const float dr = b_hh[d], dz = b_hh[d + H_], dn = b_hh[d + 2 * H_];
    for (int m = 0; m < M_; ++m) {
        float acc[6] = {0.f, 0.f, 0.f, 0.f, 0.f, 0.f};
        #pragma unroll
        for (int kk = 0; kk < 8; ++kk) {
            const float xm = vx[m * H_ + kk * 64 + lane];
            const float hm = vh[m * H_ + kk * 64 + lane];
            acc[0] = fmaf(wr[0][kk], xm, acc[0]);
            acc[1] = fmaf(wr[1][kk], xm, acc[1]);
            acc[2] = fmaf(wr[2][kk], xm, acc[2]);
            acc[3] = fmaf(wr[3][kk], hm, acc[3]);
            acc[4] = fmaf(wr[4][kk], hm, acc[4]);
            acc[5] = fmaf(wr[5][kk], hm, acc[5]);
        }
        #pragma unroll
        for (int off = 32; off; off >>= 1)
            #pragma unroll
            for (int q = 0; q < 6; ++q) acc[q] += __shfl_down(acc[q], off);
        if (lane == 0) {
            const float r  = 1.f / (1.f + expf(-(acc[0] + br + acc[3] + dr)));
            const float z  = 1.f / (1.f + expf(-(acc[1] + bz + acc[4] + dz)));
            const float ng = tanhf(acc[2] + bn + r * (acc[5] + dn));
            h[m * H_ + d] = (1.f - z) * ng + z * vh[m * H_ + d];
        }
    }
}

// 384 blocks * 256 threads, wave=row over {wq,wk,wv} x 512 rows
__global__ void qkv_kernel(const float* __restrict__ h,
                           const float* __restrict__ wq, const float* __restrict__ bq,
                           const float* __restrict__ wk, const float* __restrict__ bk,
                           const float* __restrict__ wv, const float* __restrict__ bv,
                           float* __restrict__ Q, float* __restrict__ Kk, float* __restrict__ V) {
    __shared__ float hv[M_ * H_];
    for (int idx = threadIdx.x; idx < M_ * H_; idx += blockDim.x) hv[idx] = h[idx];
    __syncthreads();
    const int gr = (blockIdx.x << 2) + (threadIdx.x >> 6);  // 0..1535
    const int lane = threadIdx.x & 63;
    const int which = gr / H_, r = gr % H_;
    const float* W = (which == 0) ? wq : ((which == 1) ? wk : wv);
    const float* B = (which == 0) ? bq : ((which == 1) ? bk : bv);
    float* O       = (which == 0) ? Q  : ((which == 1) ? Kk : V);
    float wvv[8];
    #pragma unroll
    for (int kk = 0; kk < 8; ++kk) wvv[kk] = W[(size_t)r * H_ + kk * 64 + lane];
    for (int m = 0; m < M_; ++m) {
        float acc = 0.f;
        #pragma unroll
        for (int kk = 0; kk < 8; ++kk) acc = fmaf(wvv[kk], hv[m * H_ + kk * 64 + lane], acc);
        for (int off = 32; off; off >>= 1) acc += __shfl_down(acc, off);
        if (lane == 0) O[m * H_ + r] = acc + B[r];
    }
}

// fused: coh (from Z-sums) + faction tension + attention. one block, 512 thr.
__global__ void attn_faction_kernel(const float* __restrict__ Q, const float* __restrict__ Kk,
                                    const float* __restrict__ V,
                                    const float* __restrict__ mZr, const float* __restrict__ mZi,
                                    const float* __restrict__ h, const int* __restrict__ step_p,
                                    float* __restrict__ attended, float* __restrict__ out_tension) {
    const int tid = threadIdx.x;
    __shared__ float coh_sm[M_];
    // ---- coh[m] = (sum_j |Z_j|) / (1024*512), wave w handles m=w ----
    {
        const int w = tid >> 6, lane = tid & 63;
        float s = 0.f;
        #pragma unroll
        for (int q = 0; q < 8; ++q) {
            const int j = lane + (q << 6);
            const float zr = mZr[w * D_ + j], zi = mZi[w * D_ + j];
            s += sqrtf(zr * zr + zi * zi);
        }
        #pragma unroll
        for (int off = 32; off; off >>= 1) s += __shfl_down(s, off);
        if (lane == 0) coh_sm[w] = s * (1.f / ((float)N_ * (float)D_));
    }
    __syncthreads();
    // ---- faction/tension (uses h only) ----
    {
        const int j = tid;
        const int step = *step_p;
        float h2[M_];
        #pragma unroll
        for (int ff = 0; ff < 4; ++ff) {
            const float a = h[(2*ff) * H_ + j], b = h[(2*ff+1) * H_ + j];
            const float mn = 0.5f * (a + b);
            h2[2*ff]   = 0.85f * a + 0.15f * mn;
            h2[2*ff+1] = 0.85f * b + 0.15f * mn;
        }
        if (step > 5) {
            float go = 0.f;
            #pragma unroll
            for (int m = 0; m < M_; ++m) go += h2[m];
            go *= (1.f / (float)M_);
            #pragma unroll
            for (int ff = 0; ff < 4; ++ff) h2[2*ff] = 0.85f * h2[2*ff] + 0.15f * go; // fs=2 -> dc=1
        }
        float sum = 0.f, sq = 0.f;
        #pragma unroll
        for (int m = 0; m < M_; ++m) { sum += h2[m]; sq = fmaf(h2[m], h2[m], sq); }
        __shared__ float rs[D_], rq[D_];
        rs[j] = sum; rq[j] = sq;
        __syncthreads();
        for (int s = D_/2; s > 0; s >>= 1) {
            if (j < s) { rs[j] += rs[j + s]; rq[j] += rq[j + s]; }
            __syncthreads();
        }
        if (j == 0) {
            const float Nt = (float)(M_ * H_);
            const float mean = rs[0] / Nt;
            out_tension[0] = (rq[0] - Nt * mean * mean) / (Nt - 1.f);
        }
        __syncthreads();
    }
    // ---- attention ----
    __shared__ float sc[M_][M_];
    __shared__ float colw[M_];
    const int a = tid >> 6, lane = tid & 63;
    for (int b = 0; b < M_; ++b) {
        float acc = 0.f;
        #pragma unroll
        for (int kk = 0; kk < 8; ++kk) acc = fmaf(Q[a * H_ + kk * 64 + lane], Kk[b * H_ + kk * 64 + lane], acc);
        for (int off = 32; off; off >>= 1) acc += __shfl_down(acc, off);
        if (lane == 0) sc[a][b] = acc * rsqrtf((float)H_) * (0.5f + 0.5f * coh_sm[a] * coh_sm[b]);
    }
    __syncthreads();
    if (tid < M_) {
        float mx = -1e30f;
        for (int b = 0; b < M_; ++b) mx = fmaxf(mx, sc[tid][b]);
        float e[M_], smm = 0.f;
        for (int b = 0; b < M_; ++b) { e[b] = expf(sc[tid][b] - mx); smm += e[b]; }
        for (int b = 0; b < M_; ++b) sc[tid][b] = e[b] / smm;
    }
    __syncthreads();
    if (tid < M_) {
        float sum = 0.f;
        for (int a2 = 0; a2 < M_; ++a2) sum += sc[a2][tid];
        colw[tid] = sum * (1.f / (float)M_);
    }
    __syncthreads();
    float acc = 0.f;
    #pragma unroll
    for (int b = 0; b < M_; ++b) acc = fmaf(colw[b], V[b * H_ + tid], acc);
    attended[tid] = acc;
}

// 128 blocks * 256 threads, wave=output row
__global__ void pred_kernel(const float* __restrict__ attended,
                            const float* __restrict__ out_w, const float* __restrict__ out_b,
                            float* __restrict__ pred) {
    __shared__ float av[H_];
    for (int idx = threadIdx.x; idx < H_; idx += blockDim.x) av[idx] = attended[idx];
    __syncthreads();
    const int p = (blockIdx.x << 2) + (threadIdx.x >> 6);
    const int lane = threadIdx.x & 63;
    float acc = 0.f;
    #pragma unroll
    for (int kk = 0; kk < 8; ++kk) acc = fmaf(av[kk * 64 + lane], out_w[(size_t)p * H_ + kk * 64 + lane], acc);
    for (int off = 32; off; off >>= 1) acc += __shfl_down(acc, off);
    if (lane == 0) pred[p] = acc + out_b[p];
}

// ---------------- launcher ----------------

extern "C" void kernel_launch(void* const* d_in, const int* in_sizes, int n_in,
                              void* d_out, int out_size, void* d_ws, size_t ws_size,
                              hipStream_t stream) {
    const float* x      = (const float*)d_in[0];
    const int*   step   = (const int*)  d_in[1];
    const float* amp0   = (const float*)d_in[2];
    const float* phase0 = (const float*)d_in[3];
    const float* pvel   = (const float*)d_in[4];
    const int*   nbr_i  = (const int*)  d_in[5];
    const float* nbr_m  = (const float*)d_in[6];
    const float* h0     = (const float*)d_in[7];
    const float* w_ih   = (const float*)d_in[8];
    const float* b_ih   = (const float*)d_in[9];
    const float* w_hh   = (const float*)d_in[10];
    const float* b_hh   = (const float*)d_in[11];
    const float* wq     = (const float*)d_in[12];
    const float* bq     = (const float*)d_in[13];
    const float* wk     = (const float*)d_in[14];
    const float* bk     = (const float*)d_in[15];
    const float* wv     = (const float*)d_in[16];
    const float* bv     = (const float*)d_in[17];
    const float* out_w  = (const float*)d_in[18];
    const float* out_b  = (const float*)d_in[19];
    float* out = (float*)d_out;

    const int K = in_sizes[5] / N_;   // neighbor pad width (11)
    float* ws = (float*)d_ws;

    if (ws_size >= FAST_FLOATS * sizeof(float)) {
        __half2* wCHS = (__half2*)(ws + OFF_CHS);
        float* wSIG = ws + OFF_SIG;
        float* wMA  = ws + OFF_MA;
        float* wMZR = ws + OFF_MZR;
        float* wMZI = ws + OFF_MZI;
        float* wH   = ws + OFF_H;
        float* wQ   = ws + OFF_Q;
        float* wK   = ws + OFF_K;
        float* wV   = ws + OFF_V;
        float* wATT = ws + OFF_ATT;

        prep_kernel<<<2049, 256, 0, stream>>>(phase0, pvel, x, wCHS, wMA, wSIG);
        micro_kernel<<<1024, 512, 0, stream>>>(amp0, wCHS, x, wSIG, nbr_i, nbr_m, step,
                                               wMA, wMZR, wMZI, K);
        macro_kernel<<<128, 256, 0, stream>>>(wMA, h0, w_ih, b_ih, w_hh, b_hh, wH);
        qkv_kernel<<<384, 256, 0, stream>>>(wH, wq, bq, wk, bk, wv, bv, wQ, wK, wV);
        attn_faction_kernel<<<1, 512, 0, stream>>>(wQ, wK, wV, wMZR, wMZI, wH, step, wATT, out + 512);
        pred_kernel<<<128, 256, 0, stream>>>(wATT, out_w, out_b, out);
    } else {
        float* wSIG = ws + FB_SIG;
        float* wMA  = ws + FB_MA;
        float* wMZR = ws + FB_MZR;
        float* wMZI = ws + FB_MZI;
        float* wH   = ws + FB_H;
        float* wQ   = ws + FB_Q;
        float* wK   = ws + FB_K;
        float* wV   = ws + FB_V;
        float* wATT = ws + FB_ATT;

        zero_sig_kernel<<<7, 256, 0, stream>>>(x, wMA, wSIG);
        micro_fb_kernel<<<1024, 512, 0, stream>>>(amp0, phase0, pvel, x, wSIG, nbr_i, nbr_m, step,
                                                  wMA, wMZR, wMZI, K);
        macro_kernel<<<128, 256, 0, stream>>>(wMA, h0, w_ih, b_ih, w_hh, b_hh, wH);
        qkv_kernel<<<384, 256, 0, stream>>>(wH, wq, bq, wk, bk, wv, bv, wQ, wK, wV);
        attn_faction_kernel<<<1, 512, 0, stream>>>(wQ, wK, wV, wMZR, wMZI, wH, step, wATT, out + 512);
        pred_kernel<<<128, 256, 0, stream>>>(wATT, out_w, out_b, out);
    }
}

// Round 10
// 217.552 us; speedup vs baseline: 1.1604x; 1.1604x over previous
//
#include <hip/hip_runtime.h>
#include <hip/hip_fp16.h>
#include <math.h>

#define M_  8
#define N_  1024
#define D_  512
#define H_  512
#define PI_ 3.14159265358979323846f

// ---------------- ws layouts (in floats) ----------------
// FAST path (~16.8 MB): CHS table + absum + small buffers.
static const size_t OFF_CHS = 0;                              // 4.19M half2 (16 MB)
static const size_t OFF_SIG = OFF_CHS + (size_t)M_*N_*D_;     // 1 (pad 64)
static const size_t OFF_MA  = OFF_SIG + 64;                   // 8*512  } contiguous: zeroed together
static const size_t OFF_MZR = OFF_MA  + (size_t)M_*D_;        // 8*512  }
static const size_t OFF_MZI = OFF_MZR + (size_t)M_*D_;        // 8*512  }
static const size_t OFF_ABS = OFF_MZI + (size_t)M_*D_;        // 8192 (written by prep, no zeroing)
static const size_t OFF_H   = OFF_ABS + (size_t)M_*N_;        // 8*512
static const size_t OFF_Q   = OFF_H   + (size_t)M_*H_;
static const size_t OFF_K   = OFF_Q   + (size_t)M_*H_;
static const size_t OFF_V   = OFF_K   + (size_t)M_*H_;
static const size_t OFF_ATT = OFF_V   + (size_t)M_*H_;        // 512
static const size_t FAST_FLOATS = OFF_ATT + 512;
// FALLBACK path (~120 KB): same minus CHS/ABS (absum computed in-wave there).
static const size_t FB_SIG = 0;
static const size_t FB_MA  = FB_SIG + 64;
static const size_t FB_MZR = FB_MA  + (size_t)M_*D_;
static const size_t FB_MZI = FB_MZR + (size_t)M_*D_;
static const size_t FB_H   = FB_MZI + (size_t)M_*D_;
static const size_t FB_Q   = FB_H   + (size_t)M_*H_;
static const size_t FB_K   = FB_Q   + (size_t)M_*H_;
static const size_t FB_V   = FB_K   + (size_t)M_*H_;
static const size_t FB_ATT = FB_V   + (size_t)M_*H_;

struct F8   { float4 a, b; };        // 8 consecutive floats (32 B)
struct H2x8 { __half2 h[8]; };       // 8 consecutive half2 (32 B)

__device__ __forceinline__ void unp8(float* d, const F8& v) {
    d[0]=v.a.x; d[1]=v.a.y; d[2]=v.a.z; d[3]=v.a.w;
    d[4]=v.b.x; d[5]=v.b.y; d[6]=v.b.z; d[7]=v.b.w;
}

// ---------------- fast-path kernels ----------------

// blocks 0..2047: CHS (cos,sin half2) for 2048 elems each + absum for its 4 rows.
// blocks 0..5 also zero the 12288-float accumulator region. block 2048: sigmax.
__global__ __launch_bounds__(256) void prep_kernel(const float* __restrict__ amp0,
                                                   const float* __restrict__ phase0,
                                                   const float* __restrict__ pv,
                                                   const float* __restrict__ x,
                                                   __half2* __restrict__ chs,
                                                   float* __restrict__ acczero,
                                                   float* __restrict__ absum,
                                                   float* __restrict__ sigmax) {
    const int bid = blockIdx.x, tid = threadIdx.x;
    if (bid < 2048) {
        const size_t e = ((size_t)bid * 256 + tid) * 8;       // max 4,194,296
        float ph[8], pw[8], av[8];
        unp8(ph, *reinterpret_cast<const F8*>(phase0 + e));
        unp8(pw, *reinterpret_cast<const F8*>(pv + e));
        unp8(av, *reinterpret_cast<const F8*>(amp0 + e));
        H2x8 out;
        #pragma unroll
        for (int s = 0; s < 8; ++s) {
            const float th = fmaf(0.1f, pw[s], ph[s]);
            out.h[s] = __floats2half2_rn(__cosf(th), __sinf(th));
        }
        *reinterpret_cast<H2x8*>(chs + e) = out;
        // absum: wave w reduces row bid*4 + w (64 lanes x 8 elems = 512)
        float rs = ((av[0]+av[1])+(av[2]+av[3])) + ((av[4]+av[5])+(av[6]+av[7]));
        #pragma unroll
        for (int off = 32; off; off >>= 1) rs += __shfl_down(rs, off);
        if ((tid & 63) == 0) absum[bid * 4 + (tid >> 6)] = rs;
        if (bid < 6) {
            F8 z; z.a = make_float4(0.f,0.f,0.f,0.f); z.b = z.a;
            *reinterpret_cast<F8*>(acczero + (size_t)bid * 2048 + (size_t)tid * 8) = z;
        }
    } else if (tid < 64) {
        float v[8];
        unp8(v, *reinterpret_cast<const F8*>(x + (size_t)tid * 8));
        float mx = 0.f;
        #pragma unroll
        for (int s = 0; s < 8; ++s) mx = fmaxf(mx, fabsf(v[s]));
        #pragma unroll
        for (int off = 32; off; off >>= 1) mx = fmaxf(mx, __shfl_down(mx, off));
        if (tid == 0) *sigmax = mx;
    }
}

// 1024 blocks x 256 thr (4 waves). m = bid&7 (XCD pin), g = bid>>3 in [0,128).
// Each wave owns TWO cells with interleaved k-loops (4 gathers in flight per iter).
__global__ __launch_bounds__(256) void micro_kernel(
    const float* __restrict__ amp0, const __half2* __restrict__ chs,
    const float* __restrict__ x, const float* __restrict__ sigmax_p,
    const int* __restrict__ nbr_idx, const float* __restrict__ nbr_mask,
    const int* __restrict__ step_p, const float* __restrict__ absum,
    float* __restrict__ mA, float* __restrict__ mZr, float* __restrict__ mZi, int K)
{
    const int m = blockIdx.x & 7;
    const int g = blockIdx.x >> 3;           // 0..127
    const int wid  = threadIdx.x >> 6;       // 0..3
    const int lane = threadIdx.x & 63;
    const int i0 = (g << 3) + (wid << 1);    // cells i0, i0+1
    const int i1 = i0 + 1;

    __shared__ float accA[D_], accZr[D_], accZi[D_];
    {
        const int j = threadIdx.x;
        accA[j] = 0.f; accZr[j] = 0.f; accZi[j] = 0.f;
        accA[j+256] = 0.f; accZr[j+256] = 0.f; accZi[j+256] = 0.f;
    }
    __syncthreads();

    const float t  = 0.1f * (float)(*step_p);
    const float sm = *sigmax_p;

    float pp[8];
    unp8(pp, *reinterpret_cast<const F8*>(x + (size_t)lane * 8));
    #pragma unroll
    for (int s = 0; s < 8; ++s) pp[s] = pp[s] / (sm + 1e-8f) * (PI_ * 0.1f);

    const size_t mrow = (size_t)m * N_;
    const size_t lo = (size_t)lane * 8;

    // valid-neighbor counts (mask prefix-packed 1.0s)
    int L0 = 0, L1 = 0;
    for (int k = 0; k < K; ++k) {
        L0 += (nbr_mask[i0 * K + k] > 0.f) ? 1 : 0;
        L1 += (nbr_mask[i1 * K + k] > 0.f) ? 1 : 0;
    }
    const int Lmax = (L0 > L1) ? L0 : L1;

    float SA0[8], SB0[8], SC0[8], SA1[8], SB1[8], SC1[8];
    #pragma unroll
    for (int s = 0; s < 8; ++s) {
        SA0[s]=0.f; SB0[s]=0.f; SC0[s]=0.f;
        SA1[s]=0.f; SB1[s]=0.f; SC1[s]=0.f;
    }
    float best0 = -1e30f, best1 = -1e30f; int mi0 = 0, mi1 = 0;

    for (int k = 0; k < Lmax; ++k) {
        const bool v0 = (k < L0), v1 = (k < L1);
        const int nb0 = v0 ? nbr_idx[i0 * K + k] : 0;
        const int nb1 = v1 ? nbr_idx[i1 * K + k] : 0;
        const size_t off0 = (mrow + nb0) * (size_t)D_ + lo;
        const size_t off1 = (mrow + nb1) * (size_t)D_ + lo;
        // issue all 4 gathers up front
        float a0[8], a1[8];
        unp8(a0, *reinterpret_cast<const F8*>(amp0 + off0));
        const H2x8 h0 = *reinterpret_cast<const H2x8*>(chs + off0);
        unp8(a1, *reinterpret_cast<const F8*>(amp0 + off1));
        const H2x8 h1 = *reinterpret_cast<const H2x8*>(chs + off1);
        if (v0) {
            #pragma unroll
            for (int s = 0; s < 8; ++s) {
                const float2 cs = __half22float2(h0.h[s]);
                const float ac = a0[s] * cs.x, as_ = a0[s] * cs.y;
                SA0[s] = fmaf(ac,  cs.x, SA0[s]);
                SB0[s] = fmaf(ac,  cs.y, SB0[s]);
                SC0[s] = fmaf(as_, cs.y, SC0[s]);
            }
            const float sc = absum[mrow + nb0];
            if (sc > best0) { best0 = sc; mi0 = nb0; }   // first-max
        }
        if (v1) {
            #pragma unroll
            for (int s = 0; s < 8; ++s) {
                const float2 cs = __half22float2(h1.h[s]);
                const float ac = a1[s] * cs.x, as_ = a1[s] * cs.y;
                SA1[s] = fmaf(ac,  cs.x, SA1[s]);
                SB1[s] = fmaf(ac,  cs.y, SB1[s]);
                SC1[s] = fmaf(as_, cs.y, SC1[s]);
            }
            const float sc = absum[mrow + nb1];
            if (sc > best1) { best1 = sc; mi1 = nb1; }
        }
    }

    float sA[8], sZr[8], sZi[8];
    #pragma unroll
    for (int s = 0; s < 8; ++s) { sA[s]=0.f; sZr[s]=0.f; sZi[s]=0.f; }

    #pragma unroll
    for (int cc = 0; cc < 2; ++cc) {
        const int i = cc ? i1 : i0;
        const int Lc = cc ? L1 : L0;
        const int mi = cc ? mi1 : mi0;
        const float f = 0.03f / fmaxf((float)Lc, 1.f);
        float nre[8], nim[8];
        {
            const size_t ooff = (mrow + i) * (size_t)D_ + lo;
            const size_t soff = (mrow + mi) * (size_t)D_ + lo;
            float aO[8], aS[8];
            unp8(aO, *reinterpret_cast<const F8*>(amp0 + ooff));
            const H2x8 hxo = *reinterpret_cast<const H2x8*>(chs + ooff);
            unp8(aS, *reinterpret_cast<const F8*>(amp0 + soff));
            const H2x8 hxs = *reinterpret_cast<const H2x8*>(chs + soff);
            #pragma unroll
            for (int s = 0; s < 8; ++s) {
                const float2 cs = __half22float2(hxo.h[s]);
                const float* SAp = cc ? SA1 : SA0;
                const float* SBp = cc ? SB1 : SB0;
                const float* SCp = cc ? SC1 : SC0;
                nre[s] = 0.7f * aO[s] * cs.x + f * (cs.x * SAp[s] + cs.y * SBp[s]);
                nim[s] = 0.7f * aO[s] * cs.y + f * (cs.x * SBp[s] + cs.y * SCp[s]);
            }
            // morph = new * conj(src) / |new|
            #pragma unroll
            for (int s = 0; s < 8; ++s) {
                const float2 cs = __half22float2(hxs.h[s]);
                const float sre = aS[s] * cs.x, sim = aS[s] * cs.y;
                const float inv = __builtin_amdgcn_rcpf(sqrtf(nre[s]*nre[s] + nim[s]*nim[s]));
                const float mre = (nre[s] * sre + nim[s] * sim) * inv;
                const float mim = (nim[s] * sre - nre[s] * sim) * inv;
                nre[s] = fmaf(0.02f, mre, nre[s]);
                nim[s] = fmaf(0.02f, mim, nim[s]);
            }
        }
        const float wf = 1.f + 0.02f * __sinf(t + 2.f * PI_ * (float)i / (float)N_);
        const float scale_i = 0.1f / (1.f + 0.1f * (float)i);

        float ampn[8], rm = 0.f;
        #pragma unroll
        for (int s = 0; s < 8; ++s) {
            nre[s] *= wf; nim[s] *= wf;
            ampn[s] = sqrtf(nre[s]*nre[s] + nim[s]*nim[s]);
            rm = fmaxf(rm, ampn[s]);
        }
        #pragma unroll
        for (int off = 1; off < 64; off <<= 1) rm = fmaxf(rm, __shfl_xor(rm, off));
        const float rinv = __builtin_amdgcn_rcpf(rm + 1e-8f);

        #pragma unroll
        for (int s = 0; s < 8; ++s) {
            const float anorm = ampn[s] * rinv;
            const float iamp  = __builtin_amdgcn_rcpf(ampn[s]);
            const float ure = nre[s] * iamp, uim = nim[s] * iamp;
            const float d  = pp[s] * scale_i;            // |d| <= 0.0314
            const float d2 = d * d;
            const float cd = 1.f - 0.5f * d2;
            const float sd = d * (1.f - 0.16666667f * d2);
            sA[s]  += anorm;
            sZr[s] += ure * cd - uim * sd;
            sZi[s] += ure * sd + uim * cd;
        }
    }

    #pragma unroll
    for (int s = 0; s < 8; ++s) {
        const int p = (s << 6) + lane;               // transposed slot: conflict-free
        atomicAdd(&accA[p],  sA[s]);
        atomicAdd(&accZr[p], sZr[s]);
        atomicAdd(&accZi[p], sZi[s]);
    }
    __syncthreads();
    #pragma unroll
    for (int q = 0; q < 2; ++q) {
        const int j = threadIdx.x + (q << 8);        // logical j
        const int p = ((j & 7) << 6) + (j >> 3);     // physical slot
        atomicAdd(&mA [m * D_ + j], accA[p]);
        atomicAdd(&mZr[m * D_ + j], accZr[p]);
        atomicAdd(&mZi[m * D_ + j], accZi[p]);
    }
}

// ---------------- fallback-path kernels (no CHS/absum tables) ----------------

__global__ __launch_bounds__(256) void zero_sig_kernel(const float* __restrict__ x,
                                                       float* __restrict__ acczero,
                                                       float* __restrict__ sigmax) {
    const int bid = blockIdx.x, tid = threadIdx.x;
    if (bid < 6) {
        F8 z; z.a = make_float4(0.f,0.f,0.f,0.f); z.b = z.a;
        *reinterpret_cast<F8*>(acczero + (size_t)bid * 2048 + (size_t)tid * 8) = z;
    } else if (tid < 64) {
        float v[8];
        unp8(v, *reinterpret_cast<const F8*>(x + (size_t)tid * 8));
        float mx = 0.f;
        #pragma unroll
        for (int s = 0; s < 8; ++s) mx = fmaxf(mx, fabsf(v[s]));
        #pragma unroll
        for (int off = 32; off; off >>= 1) mx = fmaxf(mx, __shfl_down(mx, off));
        if (tid == 0) *sigmax = mx;
    }
}

__global__ __launch_bounds__(512) void micro_fb_kernel(
    const float* __restrict__ amp0, const float* __restrict__ phase0,
    const float* __restrict__ pvel,
    const float* __restrict__ x, const float* __restrict__ sigmax_p,
    const int* __restrict__ nbr_idx, const float* __restrict__ nbr_mask,
    const int* __restrict__ step_p,
    float* __restrict__ mA, float* __restrict__ mZr, float* __restrict__ mZi, int K)
{
    const int m = blockIdx.x & 7;
    const int g = blockIdx.x >> 3;
    const int wid  = threadIdx.x >> 6;
    const int lane = threadIdx.x & 63;
    const int i = (g << 3) + wid;

    __shared__ float accA[D_], accZr[D_], accZi[D_];
    for (int idx = threadIdx.x; idx < D_; idx += 512) { accA[idx]=0.f; accZr[idx]=0.f; accZi[idx]=0.f; }
    __syncthreads();

    const float t  = 0.1f * (float)(*step_p);
    const float sm = *sigmax_p;

    float pp[8];
    unp8(pp, *reinterpret_cast<const F8*>(x + (size_t)lane * 8));
    #pragma unroll
    for (int s = 0; s < 8; ++s) pp[s] = pp[s] / (sm + 1e-8f) * (PI_ * 0.1f);

    const size_t mrow = (size_t)m * N_;

    int L = 0;
    for (int k = 0; k < K; ++k) L += (nbr_mask[i * K + k] > 0.f) ? 1 : 0;

    float SA[8], SB[8], SC[8];
    #pragma unroll
    for (int s = 0; s < 8; ++s) { SA[s]=0.f; SB[s]=0.f; SC[s]=0.f; }
    float best = -1e30f; int midx = 0;

    for (int k = 0; k < L; ++k) {
        const int nb = nbr_idx[i * K + k];
        const size_t noff = (mrow + nb) * (size_t)D_ + (size_t)lane * 8;
        float aN[8], phN[8], pwN[8];
        unp8(aN, *reinterpret_cast<const F8*>(amp0 + noff));
        unp8(phN, *reinterpret_cast<const F8*>(phase0 + noff));
        unp8(pwN, *reinterpret_cast<const F8*>(pvel + noff));
        #pragma unroll
        for (int s = 0; s < 8; ++s) {
            const float th = fmaf(0.1f, pwN[s], phN[s]);
            const float cn = __cosf(th), sn = __sinf(th);
            const float ac = aN[s] * cn, as_ = aN[s] * sn;
            SA[s] = fmaf(ac,  cn, SA[s]);
            SB[s] = fmaf(ac,  sn, SB[s]);
            SC[s] = fmaf(as_, sn, SC[s]);
        }
        float rs = ((aN[0]+aN[1])+(aN[2]+aN[3])) + ((aN[4]+aN[5])+(aN[6]+aN[7]));
        #pragma unroll
        for (int off = 1; off < 64; off <<= 1) rs += __shfl_xor(rs, off);
        const bool sel = rs > best;
        best = sel ? rs : best;
        midx = sel ? nb : midx;
    }
    const float f = 0.03f / fmaxf((float)L, 1.f);

    float nre[8], nim[8];
    {
        const size_t ooff = (mrow + i) * (size_t)D_ + (size_t)lane * 8;
        float aO[8], ph[8], pw[8];
        unp8(aO, *reinterpret_cast<const F8*>(amp0 + ooff));
        unp8(ph, *reinterpret_cast<const F8*>(phase0 + ooff));
        unp8(pw, *reinterpret_cast<const F8*>(pvel + ooff));
        #pragma unroll
        for (int s = 0; s < 8; ++s) {
            const float th = fmaf(0.1f, pw[s], ph[s]);
            const float c = __cosf(th), sn = __sinf(th);
            nre[s] = 0.7f * aO[s] * c  + f * (c * SA[s] + sn * SB[s]);
            nim[s] = 0.7f * aO[s] * sn + f * (c * SB[s] + sn * SC[s]);
        }
    }
    {
        const size_t soff = (mrow + midx) * (size_t)D_ + (size_t)lane * 8;
        float aS[8], ph[8], pw[8];
        unp8(aS, *reinterpret_cast<const F8*>(amp0 + soff));
        unp8(ph, *reinterpret_cast<const F8*>(phase0 + soff));
        unp8(pw, *reinterpret_cast<const F8*>(pvel + soff));
        #pragma unroll
        for (int s = 0; s < 8; ++s) {
            const float th = fmaf(0.1f, pw[s], ph[s]);
            const float c = __cosf(th), sn = __sinf(th);
            const float sre = aS[s] * c, sim = aS[s] * sn;
            const float inv = __builtin_amdgcn_rcpf(sqrtf(nre[s]*nre[s] + nim[s]*nim[s]));
            const float mre = (nre[s] * sre + nim[s] * sim) * inv;
            const float mim = (nim[s] * sre - nre[s] * sim) * inv;
            nre[s] = fmaf(0.02f, mre, nre[s]);
            nim[s] = fmaf(0.02f, mim, nim[s]);
        }
    }

    const float wf = 1.f + 0.02f * __sinf(t + 2.f * PI_ * (float)i / (float)N_);
    const float scale_i = 0.1f / (1.f + 0.1f * (float)i);

    float ampn[8], rm = 0.f;
    #pragma unroll
    for (int s = 0; s < 8; ++s) {
        nre[s] *= wf; nim[s] *= wf;
        ampn[s] = sqrtf(nre[s]*nre[s] + nim[s]*nim[s]);
        rm = fmaxf(rm, ampn[s]);
    }
    #pragma unroll
    for (int off = 1; off < 64; off <<= 1) rm = fmaxf(rm, __shfl_xor(rm, off));
    const float rinv = __builtin_amdgcn_rcpf(rm + 1e-8f);

    #pragma unroll
    for (int s = 0; s < 8; ++s) {
        const float anorm = ampn[s] * rinv;
        const float iamp  = __builtin_amdgcn_rcpf(ampn[s]);
        const float ure = nre[s] * iamp, uim = nim[s] * iamp;
        const float d  = pp[s] * scale_i;
        const float d2 = d * d;
        const float cd = 1.f - 0.5f * d2;
        const float sd = d * (1.f - 0.16666667f * d2);
        const int p = (s << 6) + lane;
        atomicAdd(&accA[p],  anorm);
        atomicAdd(&accZr[p], ure * cd - uim * sd);
        atomicAdd(&accZi[p], ure * sd + uim * cd);
    }
    __syncthreads();
    const int j = threadIdx.x;
    const int p = ((j & 7) << 6) + (j >> 3);
    atomicAdd(&mA [m * D_ + j], accA[p]);
    atomicAdd(&mZr[m * D_ + j], accZr[p]);
    atomicAdd(&mZi[m * D_ + j], accZi[p]);
}

// ---------------- shared macro-side kernels ----------------

__global__ __launch_bounds__(256) void macro_kernel(
    const float* __restrict__ mA, const float* __restrict__ h0,
    const float* __restrict__ w_ih, const float* __restrict__ b_ih,
    const float* __restrict__ w_hh, const float* __restrict__ b_hh,
    float* __restrict__ h)
{
    __shared__ float vx[M_ * H_], vh[M_ * H_];
    for (int idx = threadIdx.x; idx < M_ * H_; idx += 256) {
        vx[idx] = mA[idx] * (1.f / (float)N_);       // micro_out = A-sum / 1024
        vh[idx] = h0[idx];
    }
    __syncthreads();
    const int wid = threadIdx.x >> 6, lane = threadIdx.x & 63;
    const int d = (blockIdx.x << 2) + wid;   // 0..511
    float wr[6][8];
    #pragma unroll
    for (int rr = 0; rr < 3; ++rr) {
        const size_t row = (size_t)(d + rr * H_) * H_;
        #pragma unroll
        for (int kk = 0; kk < 8; ++kk) {
            wr[rr][kk]     = w_ih[row + kk * 64 + lane];
            wr[rr + 3][kk] = w_hh[row + kk * 64 + lane];
        }
    }
    const float br = b_ih[d], bz = b_ih[d + H_], bn = b_ih[d + 2 * H_];
    const float dr = b_hh[d], dz = b_hh[d + H_], dn = b_hh[d + 2 * H_];
    for (int m = 0; m < M_; ++m) {
        float acc[6] = {0.f, 0.f, 0.f, 0.f, 0.f, 0.f};
        #pragma unroll
        for (int kk = 0; kk < 8; ++kk) {
            const float xm = vx[m * H_ + kk * 64 + lane];
            const float hm = vh[m * H_ + kk * 64 + lane];
            acc[0] = fmaf(wr[0][kk], xm, acc[0]);
            acc[1] = fmaf(wr[1][kk], xm, acc[1]);
            acc[2] = fmaf(wr[2][kk], xm, acc[2]);
            acc[3] = fmaf(wr[3][kk], hm, acc[3]);
            acc[4] = fmaf(wr[4][kk], hm, acc[4]);
            acc[5] = fmaf(wr[5][kk], hm, acc[5]);
        }
        #pragma unroll
        for (int off = 32; off; off >>= 1)
            #pragma unroll
            for (int q = 0; q < 6; ++q) acc[q] += __shfl_down(acc[q], off);
        if (lane == 0) {
            const float r  = 1.f / (1.f + expf(-(acc[0] + br + acc[3] + dr)));
            const float z  = 1.f / (1.f + expf(-(acc[1] + bz + acc[4] + dz)));
            const float ng = tanhf(acc[2] + bn + r * (acc[5] + dn));
            h[m * H_ + d] = (1.f - z) * ng + z * vh[m * H_ + d];
        }
    }
}

__global__ void qkv_kernel(const float* __restrict__ h,
                           const float* __restrict__ wq, const float* __restrict__ bq,
                           const float* __restrict__ wk, const float* __restrict__ bk,
                           const float* __restrict__ wv, const float* __restrict__ bv,
                           float* __restrict__ Q, float* __restrict__ Kk, float* __restrict__ V) {
    __shared__ float hv[M_ * H_];
    for (int idx = threadIdx.x; idx < M_ * H_; idx += blockDim.x) hv[idx] = h[idx];
    __syncthreads();
    const int gr = (blockIdx.x << 2) + (threadIdx.x >> 6);  // 0..1535
    const int lane = threadIdx.x & 63;
    const int which = gr / H_, r = gr % H_;
    const float* W = (which == 0) ? wq : ((which == 1) ? wk : wv);
    const float* B = (which == 0) ? bq : ((which == 1) ? bk : bv);
    float* O       = (which == 0) ? Q  : ((which == 1) ? Kk : V);
    float wvv[8];
    #pragma unroll
    for (int kk = 0; kk < 8; ++kk) wvv[kk] = W[(size_t)r * H_ + kk * 64 + lane];
    for (int m = 0; m < M_; ++m) {
        float acc = 0.f;
        #pragma unroll
        for (int kk = 0; kk < 8; ++kk) acc = fmaf(wvv[kk], hv[m * H_ + kk * 64 + lane], acc);
        for (int off = 32; off; off >>= 1) acc += __shfl_down(acc, off);
        if (lane == 0) O[m * H_ + r] = acc + B[r];
    }
}

__global__ void attn_faction_kernel(const float* __restrict__ Q, const float* __restrict__ Kk,
                                    const float* __restrict__ V,
                                    const float* __restrict__ mZr, const float* __restrict__ mZi,
                                    const float* __restrict__ h, const int* __restrict__ step_p,
                                    float* __restrict__ attended, float* __restrict__ out_tension) {
    const int tid = threadIdx.x;
    __shared__ float coh_sm[M_];
    {
        const int w = tid >> 6, lane = tid & 63;
        float s = 0.f;
        #pragma unroll
        for (int q = 0; q < 8; ++q) {
            const int j = lane + (q << 6);
            const float zr = mZr[w * D_ + j], zi = mZi[w * D_ + j];
            s += sqrtf(zr * zr + zi * zi);
        }
        #pragma unroll
        for (int off = 32; off; off >>= 1) s += __shfl_down(s, off);
        if (lane == 0) coh_sm[w] = s * (1.f / ((float)N_ * (float)D_));
    }
    __syncthreads();
    {
        const int j = tid;
        const int step = *step_p;
        float h2[M_];
        #pragma unroll
        for (int ff = 0; ff < 4; ++ff) {
            const float a = h[(2*ff) * H_ + j], b = h[(2*ff+1) * H_ + j];
            const float mn = 0.5f * (a + b);
            h2[2*ff]   = 0.85f * a + 0.15f * mn;
            h2[2*ff+1] = 0.85f * b + 0.15f * mn;
        }
        if (step > 5) {
            float go = 0.f;
            #pragma unroll
            for (int m = 0; m < M_; ++m) go += h2[m];
            go *= (1.f / (float)M_);
            #pragma unroll
            for (int ff = 0; ff < 4; ++ff) h2[2*ff] = 0.85f * h2[2*ff] + 0.15f * go; // fs=2 -> dc=1
        }
        float sum = 0.f, sq = 0.f;
        #pragma unroll
        for (int m = 0; m < M_; ++m) { sum += h2[m]; sq = fmaf(h2[m], h2[m], sq); }
        __shared__ float rs[D_], rq[D_];
        rs[j] = sum; rq[j] = sq;
        __syncthreads();
        for (int s = D_/2; s > 0; s >>= 1) {
            if (j < s) { rs[j] += rs[j + s]; rq[j] += rq[j + s]; }
            __syncthreads();
        }
        if (j == 0) {
            const float Nt = (float)(M_ * H_);
            const float mean = rs[0] / Nt;
            out_tension[0] = (rq[0] - Nt * mean * mean) / (Nt - 1.f);
        }
        __syncthreads();
    }
    __shared__ float sc[M_][M_];
    __shared__ float colw[M_];
    const int a = tid >> 6, lane = tid & 63;
    for (int b = 0; b < M_; ++b) {
        float acc = 0.f;
        #pragma unroll
        for (int kk = 0; kk < 8; ++kk) acc = fmaf(Q[a * H_ + kk * 64 + lane], Kk[b * H_ + kk * 64 + lane], acc);
        for (int off = 32; off; off >>= 1) acc += __shfl_down(acc, off);
        if (lane == 0) sc[a][b] = acc * rsqrtf((float)H_) * (0.5f + 0.5f * coh_sm[a] * coh_sm[b]);
    }
    __syncthreads();
    if (tid < M_) {
        float mx = -1e30f;
        for (int b = 0; b < M_; ++b) mx = fmaxf(mx, sc[tid][b]);
        float e[M_], smm = 0.f;
        for (int b = 0; b < M_; ++b) { e[b] = expf(sc[tid][b] - mx); smm += e[b]; }
        for (int b = 0; b < M_; ++b) sc[tid][b] = e[b] / smm;
    }
    __syncthreads();
    if (tid < M_) {
        float sum = 0.f;
        for (int a2 = 0; a2 < M_; ++a2) sum += sc[a2][tid];
        colw[tid] = sum * (1.f / (float)M_);
    }
    __syncthreads();
    float acc = 0.f;
    #pragma unroll
    for (int b = 0; b < M_; ++b) acc = fmaf(colw[b], V[b * H_ + tid], acc);
    attended[tid] = acc;
}

__global__ void pred_kernel(const float* __restrict__ attended,
                            const float* __restrict__ out_w, const float* __restrict__ out_b,
                            float* __restrict__ pred) {
    __shared__ float av[H_];
    for (int idx = threadIdx.x; idx < H_; idx += blockDim.x) av[idx] = attended[idx];
    __syncthreads();
    const int p = (blockIdx.x << 2) + (threadIdx.x >> 6);
    const int lane = threadIdx.x & 63;
    float acc = 0.f;
    #pragma unroll
    for (int kk = 0; kk < 8; ++kk) acc = fmaf(av[kk * 64 + lane], out_w[(size_t)p * H_ + kk * 64 + lane], acc);
    for (int off = 32; off; off >>= 1) acc += __shfl_down(acc, off);
    if (lane == 0) pred[p] = acc + out_b[p];
}

// ---------------- launcher ----------------

extern "C" void kernel_launch(void* const* d_in, const int* in_sizes, int n_in,
                              void* d_out, int out_size, void* d_ws, size_t ws_size,
                              hipStream_t stream) {
    const float* x      = (const float*)d_in[0];
    const int*   step   = (const int*)  d_in[1];
    const float* amp0   = (const float*)d_in[2];
    const float* phase0 = (const float*)d_in[3];
    const float* pvel   = (const float*)d_in[4];
    const int*   nbr_i  = (const int*)  d_in[5];
    const float* nbr_m  = (const float*)d_in[6];
    const float* h0     = (const float*)d_in[7];
    const float* w_ih   = (const float*)d_in[8];
    const float* b_ih   = (const float*)d_in[9];
    const float* w_hh   = (const float*)d_in[10];
    const float* b_hh   = (const float*)d_in[11];
    const float* wq     = (const float*)d_in[12];
    const float* bq     = (const float*)d_in[13];
    const float* wk     = (const float*)d_in[14];
    const float* bk     = (const float*)d_in[15];
    const float* wv     = (const float*)d_in[16];
    const float* bv     = (const float*)d_in[17];
    const float* out_w  = (const float*)d_in[18];
    const float* out_b  = (const float*)d_in[19];
    float* out = (float*)d_out;

    const int K = in_sizes[5] / N_;   // neighbor pad width (11)
    float* ws = (float*)d_ws;

    if (ws_size >= FAST_FLOATS * sizeof(float)) {
        __half2* wCHS = (__half2*)(ws + OFF_CHS);
        float* wSIG = ws + OFF_SIG;
        float* wMA  = ws + OFF_MA;
        float* wMZR = ws + OFF_MZR;
        float* wMZI = ws + OFF_MZI;
        float* wABS = ws + OFF_ABS;
        float* wH   = ws + OFF_H;
        float* wQ   = ws + OFF_Q;
        float* wK   = ws + OFF_K;
        float* wV   = ws + OFF_V;
        float* wATT = ws + OFF_ATT;

        prep_kernel<<<2049, 256, 0, stream>>>(amp0, phase0, pvel, x, wCHS, wMA, wABS, wSIG);
        micro_kernel<<<1024, 256, 0, stream>>>(amp0, wCHS, x, wSIG, nbr_i, nbr_m, step,
                                               wABS, wMA, wMZR, wMZI, K);
        macro_kernel<<<128, 256, 0, stream>>>(wMA, h0, w_ih, b_ih, w_hh, b_hh, wH);
        qkv_kernel<<<384, 256, 0, stream>>>(wH, wq, bq, wk, bk, wv, bv, wQ, wK, wV);
        attn_faction_kernel<<<1, 512, 0, stream>>>(wQ, wK, wV, wMZR, wMZI, wH, step, wATT, out + 512);
        pred_kernel<<<128, 256, 0, stream>>>(wATT, out_w, out_b, out);
    } else {
        float* wSIG = ws + FB_SIG;
        float* wMA  = ws + FB_MA;
        float* wMZR = ws + FB_MZR;
        float* wMZI = ws + FB_MZI;
        float* wH   = ws + FB_H;
        float* wQ   = ws + FB_Q;
        float* wK   = ws + FB_K;
        float* wV   = ws + FB_V;
        float* wATT = ws + FB_ATT;

        zero_sig_kernel<<<7, 256, 0, stream>>>(x, wMA, wSIG);
        micro_fb_kernel<<<1024, 512, 0, stream>>>(amp0, phase0, pvel, x, wSIG, nbr_i, nbr_m, step,
                                                  wMA, wMZR, wMZI, K);
        macro_kernel<<<128, 256, 0, stream>>>(wMA, h0, w_ih, b_ih, w_hh, b_hh, wH);
        qkv_kernel<<<384, 256, 0, stream>>>(wH, wq, bq, wk, bk, wv, bv, wQ, wK, wV);
        attn_faction_kernel<<<1, 512, 0, stream>>>(wQ, wK, wV, wMZR, wMZI, wH, step, wATT, out + 512);
        pred_kernel<<<128, 256, 0, stream>>>(wATT, out_w, out_b, out);
    }
}